// Round 14
// baseline (501.335 us; speedup 1.0000x reference)
//
#include <hip/hip_runtime.h>

#define B_ 8
#define N_ 16384
#define F_ 6
#define M_ 128
#define K_ 16
#define D_ 768

typedef unsigned short u16;
typedef unsigned int u32;
typedef unsigned long long u64;
typedef __attribute__((ext_vector_type(8))) short short8;
typedef __attribute__((ext_vector_type(4))) float f32x4;
typedef __attribute__((ext_vector_type(2))) float f32x2;

__device__ __forceinline__ u16 f2bf(float f){
  union { float f; u32 i; } v; v.f = f;
  u32 x = v.i;
  u32 r = x + 0x7FFFu + ((x >> 16) & 1u);
  return (u16)(r >> 16);
}

// async 16B global->LDS (dest = wave-uniform base + lane*16)
__device__ __forceinline__ void ld_g2l(const u16* g, u16* l){
  __builtin_amdgcn_global_load_lds((const __attribute__((address_space(1))) u32*)g,
                                   (__attribute__((address_space(3))) u32*)l, 16, 0, 0);
}

// VOLATILE asm 16B load: result cannot be rematerialized from memory by LLVM.
__device__ __forceinline__ f32x4 ld_x4(const float* p){
  f32x4 r;
  asm volatile("global_load_dwordx4 %0, %1, off" : "=v"(r) : "v"(p) : "memory");
  return r;
}

// DPP self-max/min steps (chain row_shr:1,2,4,8 + row_bcast:15,31 -> result in lane 63;
// harness-verified rounds 6/7/10/11/12/13).
template<int CTRL>
__device__ __forceinline__ float dppmax(float v){
  union { float f; int i; } a, r;
  a.f = v;
  r.i = __builtin_amdgcn_update_dpp(a.i, a.i, CTRL, 0xF, 0xF, false);
  return fmaxf(v, r.f);
}
template<int CTRL>
__device__ __forceinline__ float dppmin(float v){
  union { float f; int i; } a, r;
  a.f = v;
  r.i = __builtin_amdgcn_update_dpp(a.i, a.i, CTRL, 0xF, 0xF, false);
  return fminf(v, r.f);
}
template<int CTRL>
__device__ __forceinline__ int dppimin(int v){
  int r = __builtin_amdgcn_update_dpp(v, v, CTRL, 0xF, 0xF, false);
  return (r < v) ? r : v;
}

// Publish one centroid: 4 self-validating u64 words ((m+1)<<32 | float_bits), relaxed
// agent-scope stores. Each word carries its own tag -> partial visibility is safe.
__device__ __forceinline__ void pub_cent(u64* pb, int m, float x, float y, float z, float w){
  union { float f; u32 u; } c0, c1, c2, c3;
  c0.f = x; c1.f = y; c2.f = z; c3.f = w;
  u64 tag = ((u64)(u32)(m + 1)) << 32;
  __hip_atomic_store(pb + 0, tag | c0.u, __ATOMIC_RELAXED, __HIP_MEMORY_SCOPE_AGENT);
  __hip_atomic_store(pb + 1, tag | c1.u, __ATOMIC_RELAXED, __HIP_MEMORY_SCOPE_AGENT);
  __hip_atomic_store(pb + 2, tag | c2.u, __ATOMIC_RELAXED, __HIP_MEMORY_SCOPE_AGENT);
  __hip_atomic_store(pb + 3, tag | c3.u, __ATOMIC_RELAXED, __HIP_MEMORY_SCOPE_AGENT);
}

// ---------------- zero the centroid publish slots (stale tags across graph replays) ----------------
__global__ __launch_bounds__(256) void zero_pub(u64* __restrict__ pub){
  pub[(size_t)blockIdx.x * 256 + threadIdx.x] = 0ull;
}

// ---------------- MEGA-FUSED: FPS (0..7) + weight conv (8..567) + knn workers (568..815) ----------------
// r12 lesson (Occupancy 0.75->17.6%, fps 259->331): knn/conv blocks CO-RESIDED on the fps
// CUs and stole issue slots. r13's extern-shared pad was DCE'd (LDS_Block_Size stayed
// 10752) -> fence never existed. r14 fix: a static 84KB LDS arena that IS used (all
// shared vars alias into it at fixed offsets) -> cannot be eliminated -> every block
// owns 84KB > 80KB -> hardware enforces 1 block/CU. Termination is dispatch-order-
// independent: conv never spins and drains; spinners(248 knn) + fps(8) = 256 <= 256 CUs.
#define FPT 32   // fps: points per thread (512 thr)
#define KNW 248  // knn worker blocks
#define KNT 512
#define KPT 32
__global__ __launch_bounds__(512)
void fps_conv(const float* __restrict__ coords,
              float* __restrict__ out, size_t out_elems,
              const float* __restrict__ W1, const float* __restrict__ W2,
              const float* __restrict__ W3, const float* __restrict__ Wn0,
              const float* __restrict__ Wn1, u16* __restrict__ Wb,
              u64* __restrict__ cpub, int* __restrict__ invp,
              int* __restrict__ knn_fps){
#pragma clang fp contract(off)
  // 84KB occupancy fence: 2 blocks would need 168KB > 160KB -> 1 block/CU guaranteed.
  __shared__ __attribute__((aligned(16))) char smem[86016];
  u16 (*tile)[65] = (u16(*)[65])smem;                  // conv: 64x65 u16 = 8320 B (conv-only)
  f32x4* carr     = (f32x4*)smem;                      // fps: 2048 B (fps-only; disjoint branch)
  float (*swv)[8] = (float(*)[8])(smem + 8320);        // fps+knn: 64 B
  int   (*swi)[8] = (int(*)[8])(smem + 8384);          // fps+knn: 64 B
  int*   s_bi     = (int*)(smem + 8448);
  f32x4* scent    = (f32x4*)(smem + 8464);
  int blk = blockIdx.x;
  int t = threadIdx.x;

  if (blk >= 8 && blk < 568){
    // ---------------- weight conversion branch (512 threads) ----------------
    int cblk = blk - 8;
    const float* W; u16* WT; int K, N, lb;
    if      (cblk < 32)  { W = W1;  WT = Wb;           K = 256; N = 512; lb = cblk; }
    else if (cblk < 128) { W = W2;  WT = Wb + 131072;  K = 512; N = 768; lb = cblk - 32; }
    else if (cblk < 272) { W = W3;  WT = Wb + 524288;  K = 768; N = 768; lb = cblk - 128; }
    else if (cblk < 416) { W = Wn0; WT = Wb + 1114112; K = 768; N = 768; lb = cblk - 272; }
    else                 { W = Wn1; WT = Wb + 1703936; K = 768; N = 768; lb = cblk - 416; }
    int tiles_n = N >> 6;
    int tk = lb / tiles_n, tn = lb % tiles_n;
    int k0 = tk << 6, n0 = tn << 6;
#pragma unroll
    for (int q = 0; q < 8; q++){
      int idx = q * 512 + t;
      int kk = idx >> 6, nn = idx & 63;
      tile[kk][nn] = f2bf(W[(size_t)(k0 + kk) * N + n0 + nn]);
    }
    __syncthreads();
#pragma unroll
    for (int q = 0; q < 8; q++){
      int idx = q * 512 + t;
      int nn = idx >> 6, kk = idx & 63;
      WT[(size_t)(n0 + nn) * K + k0 + kk] = tile[kk][nn];
    }
    return;
  }

  if (blk >= 568){
    // ---------------- knn worker branch: poll centroids, compute kNN (FPS order) ----------------
    int w = blk - 568;
    for (int p = w; p < B_ * M_; p += KNW){
      int m = p >> 3, b = p & 7;
      if (t == 0){
        const u64* pb = cpub + (((size_t)b << 7) + m) * 4;
        u32 want = (u32)(m + 1);
        u64 v0, v1, v2, v3;
        for (;;){
          v0 = __hip_atomic_load(pb + 0, __ATOMIC_RELAXED, __HIP_MEMORY_SCOPE_AGENT);
          v1 = __hip_atomic_load(pb + 1, __ATOMIC_RELAXED, __HIP_MEMORY_SCOPE_AGENT);
          v2 = __hip_atomic_load(pb + 2, __ATOMIC_RELAXED, __HIP_MEMORY_SCOPE_AGENT);
          v3 = __hip_atomic_load(pb + 3, __ATOMIC_RELAXED, __HIP_MEMORY_SCOPE_AGENT);
          if ((u32)(v0 >> 32) == want && (u32)(v1 >> 32) == want &&
              (u32)(v2 >> 32) == want && (u32)(v3 >> 32) == want) break;
          __builtin_amdgcn_s_sleep(2);
        }
        union { u32 u; float f; } d0, d1, d2, d3;
        d0.u = (u32)v0; d1.u = (u32)v1; d2.u = (u32)v2; d3.u = (u32)v3;
        *scent = (f32x4){d0.f, d1.f, d2.f, d3.f};
      }
      __syncthreads();
      float cx = (*scent)[0], cy = (*scent)[1], cz = (*scent)[2], ct = (*scent)[3];
      const float* cb = coords + (size_t)b * N_ * 5;
      float dist[KPT];
#pragma unroll
      for (int j = 0; j < KPT; j++){
        size_t i = t + j * KNT;
        float dx=cb[i*5+1]-cx, dy=cb[i*5+2]-cy, dz=cb[i*5+3]-cz, dw=cb[i*5+4]-ct;
        float d = ((dx*dx + dy*dy) + dz*dz) + dw*dw;
        dist[j] = sqrtf(d);                          // IEEE f32 sqrt = np.sqrt(f32)
      }
      for (int r = 0; r < K_; r++){
        float bv = 3e38f; int bi = 1 << 30;
#pragma unroll
        for (int j = 0; j < KPT; j++){
          int i = t + j * KNT;
          float v = dist[j];
          if (v < bv){ bv = v; bi = i; }             // first-min kept (ascending own indices)
        }
        // value min via DPP; ties -> integer index-min DPP (lane order != index order)
        float rv = bv;
        rv = dppmin<0x111>(rv); rv = dppmin<0x112>(rv); rv = dppmin<0x114>(rv);
        rv = dppmin<0x118>(rv); rv = dppmin<0x142>(rv); rv = dppmin<0x143>(rv);
        union { float f; int i; } rmu; rmu.f = rv;
        union { int i; float f; } wmn; wmn.i = __builtin_amdgcn_readlane(rmu.i, 63);
        float wmin = wmn.f;
        int cand = (bv == wmin) ? bi : 0x7FFFFFFF;
        cand = dppimin<0x111>(cand); cand = dppimin<0x112>(cand); cand = dppimin<0x114>(cand);
        cand = dppimin<0x118>(cand); cand = dppimin<0x142>(cand); cand = dppimin<0x143>(cand);
        int wbi = __builtin_amdgcn_readlane(cand, 63);
        if ((t & 63) == 0){ swv[0][t >> 6] = wmin; swi[0][t >> 6] = wbi; }
        __syncthreads();
        if (t == 0){
          float fv = swv[0][0]; int fi = swi[0][0];
          for (int ww = 1; ww < 8; ww++){
            float wv = swv[0][ww]; int wi = swi[0][ww];
            if (wv < fv || (wv == fv && wi < fi)){ fv = wv; fi = wi; }
          }
          *s_bi = fi;
          knn_fps[(((size_t)b << 7) + m) * K_ + r] = fi & (N_ - 1);
        }
        __syncthreads();
        int wi = *s_bi;
#pragma unroll
        for (int j = 0; j < KPT; j++){
          if (t + j * KNT == wi) dist[j] = 3e38f;
        }
      }
    }
    return;
  }

  // ---------------- FPS branch (round-7 verbatim core + publish) ----------------
  int b = blk;
  int lane = t & 63, wave = t >> 6;
  const float* cb = coords + (size_t)b * N_ * 5;
  const int base = t << 5;                       // first point index owned by this thread
  f32x4 p[FPT];
#pragma unroll
  for (int k = 0; k < FPT; k++){
    p[k] = ld_x4(cb + (size_t)(base + k) * 5 + 1);   // (x,y,z,w) of point base+k
  }
  float md[FPT];
#pragma unroll
  for (int k = 0; k < FPT; k++) md[k] = 1e30f;
  asm volatile("s_waitcnt vmcnt(0)" ::: "memory");   // drain the asm loads
  __builtin_amdgcn_sched_barrier(0);                 // rule #18: pin uses after the wait
  float cx = cb[1], cy = cb[2], cz = cb[3], ct = cb[4];
  if (t == 0){
    carr[0] = (f32x4){cx, cy, cz, ct};
    pub_cent(cpub + ((size_t)b << 7) * 4, 0, cx, cy, cz, ct);
  }
  for (int step = 1; step < M_; step++){
    float bv = -1.0f; int bl = 0;
#pragma unroll
    for (int k = 0; k < FPT; k++){
      float dx = p[k][0] - cx;
      float dy = p[k][1] - cy;
      float dz = p[k][2] - cz;
      float dw = p[k][3] - ct;
      float s = ((dx*dx + dy*dy) + dz*dz) + dw*dw;   // reference rounding order
      float m = fminf(s, md[k]);
      md[k] = m;
      if (m > bv){ bv = m; bl = k; }                 // ascending-index first-max
    }
    int bi = base + bl;                              // global point index
    float r = bv;
    r = dppmax<0x111>(r); r = dppmax<0x112>(r); r = dppmax<0x114>(r);
    r = dppmax<0x118>(r); r = dppmax<0x142>(r); r = dppmax<0x143>(r);
    union { float f; int i; } rm; rm.f = r;
    union { int i; float f; } wmu; wmu.i = __builtin_amdgcn_readlane(rm.i, 63);
    float wmax = wmu.f;                              // uniform (SGPR)
    u64 wmask = __ballot(bv == wmax);
    int srcL = (int)__ffsll((unsigned long long)wmask) - 1;  // lowest lane = lowest index
    int wbi = __builtin_amdgcn_readlane(bi, srcL);   // uniform winner index of this wave
    int par = step & 1;
    if (lane == 0){ swv[par][wave] = wmax; swi[par][wave] = wbi; }
    __syncthreads();                                 // only barrier per step
    float fv = swv[par][0]; int fi = swi[par][0];
#pragma unroll
    for (int w = 1; w < 8; w++){
      float v = swv[par][w];
      int  iw = swi[par][w];
      if (v > fv){ fv = v; fi = iw; }                // strict > keeps lowest wave (= lowest index)
    }
    int widx = __builtin_amdgcn_readfirstlane(fi);
    size_t wb = (size_t)widx * 5;
    cx = cb[wb+1]; cy = cb[wb+2]; cz = cb[wb+3]; ct = cb[wb+4];
    if (t == 0){
      carr[step] = (f32x4){cx, cy, cz, ct};
      pub_cent(cpub + (((size_t)b << 7) + step) * 4, step, cx, cy, cz, ct);
    }
  }
  // ---- fused rank tail: stable argsort by centroid time -> out + invp ----
  __syncthreads();
  if (t < M_){
    f32x4 row = carr[t];
    float w = row[3];
    int rank = 0;
    for (int j = 0; j < M_; j++){
      float tj = carr[j][3];
      if (tj < w || (tj == w && j < t)) rank++;      // stable argsort semantics
    }
    invp[(b << 7) + rank] = t;                       // sorted pos -> fps index
    size_t co = (size_t)B_ * M_ * D_ + ((size_t)b * M_ + rank) * 4;
    if (co + 3 < out_elems){
      out[co+0]=row[0]; out[co+1]=row[1]; out[co+2]=row[2]; out[co+3]=w;
    }
    size_t mo = (size_t)B_ * M_ * D_ + (size_t)B_ * M_ * 4 + (size_t)b * M_ + t;
    if (mo < out_elems) out[mo] = 1.0f;              // mask = True -> 1.0f
  }
}

// ---------------- gather + layer0: 32 rows/block; knn in FPS order, remap via invp ----------------
__global__ __launch_bounds__(256) void gather_l0(const float* __restrict__ feat,
                                                 const int* __restrict__ knn,
                                                 const int* __restrict__ invp,
                                                 const float* __restrict__ W0,
                                                 const float* __restrict__ b0,
                                                 u16* __restrict__ h1,
                                                 int rowBase){
  __shared__ float sW[F_][256];
  __shared__ float sb[256];
  __shared__ float sfa[32][F_];
  int t = threadIdx.x;
#pragma unroll
  for (int k = 0; k < F_; k++) sW[k][t] = W0[k * 256 + t];
  sb[t] = b0[t];
  if (t < 32 * F_){
    int r = t / F_, k = t % F_;
    int grow = rowBase + blockIdx.x * 32 + r;
    int bb = grow >> 11;                          // /(M*K)=2048
    int ms = (grow >> 4) & 127;                   // sorted centroid position
    int kk = grow & 15;
    int mf = invp[(bb << 7) + ms];                // fps-order centroid index
    int idx = knn[((((size_t)bb << 7) + mf) << 4) + kk] & (N_ - 1);
    sfa[r][k] = feat[((size_t)bb * N_ + idx) * F_ + k];
  }
  __syncthreads();
#pragma unroll 4
  for (int r = 0; r < 32; r++){
    float acc = sb[t];
#pragma unroll
    for (int k = 0; k < F_; k++) acc = fmaf(sfa[r][k], sW[k][t], acc);
    int lrow = blockIdx.x * 32 + r;
    h1[(size_t)lrow * 256 + t] = f2bf(fmaxf(acc, 0.0f));
  }
}

// ---------------- bf16 MFMA GEMM (128x128), async global->LDS staging ----------------
template<int RELU, int OUTF32>
__global__ __launch_bounds__(256) void gemm_bf16(const u16* __restrict__ A,
                                                 const u16* __restrict__ WT,
                                                 const float* __restrict__ bias,
                                                 void* __restrict__ Cv,
                                                 int Kd, int Nd){
  __shared__ u16 As[128][32];
  __shared__ u16 Bs[128][32];
  const int t = threadIdx.x;
  const int bm = blockIdx.y << 7;
  const int bn = blockIdx.x << 7;
  const int wave = t >> 6;
  const int lane = t & 63;
  const int wm = (wave & 1) << 6;
  const int wn = (wave >> 1) << 6;
  const int lm = lane & 15;
  const int lk = (lane >> 4) << 3;
  u16* AsF = &As[0][0];
  u16* BsF = &Bs[0][0];
  const int wbase = wave << 6;               // t - lane
  f32x4 acc[4][4] = {};
  for (int k0 = 0; k0 < Kd; k0 += 32){
#pragma unroll
    for (int it = 0; it < 2; it++){
      int slot = t + (it << 8);
      int r = slot >> 2;
      int c = (slot & 3) << 3;
      int dst = (wbase + (it << 8)) << 3;    // u16 elements; +lane*16B by HW
      ld_g2l(A  + (size_t)(bm + r) * Kd + k0 + c, AsF + dst);
      ld_g2l(WT + (size_t)(bn + r) * Kd + k0 + c, BsF + dst);
    }
    __syncthreads();
    short8 af[4], bfr[4];
#pragma unroll
    for (int mt = 0; mt < 4; mt++) af[mt] = *(const short8*)&As[wm + (mt << 4) + lm][lk];
#pragma unroll
    for (int nt = 0; nt < 4; nt++) bfr[nt] = *(const short8*)&Bs[wn + (nt << 4) + lm][lk];
#pragma unroll
    for (int mt = 0; mt < 4; mt++)
#pragma unroll
      for (int nt = 0; nt < 4; nt++)
        acc[mt][nt] = __builtin_amdgcn_mfma_f32_16x16x32_bf16(af[mt], bfr[nt], acc[mt][nt], 0, 0, 0);
    __syncthreads();
  }
#pragma unroll
  for (int nt = 0; nt < 4; nt++){
    int n = bn + wn + (nt << 4) + lm;
    float bia = bias[n];
#pragma unroll
    for (int mt = 0; mt < 4; mt++){
#pragma unroll
      for (int r2 = 0; r2 < 4; r2++){
        int m = bm + wm + (mt << 4) + ((lane >> 4) << 2) + r2;
        float v = acc[mt][nt][r2] + bia;
        if (RELU) v = fmaxf(v, 0.0f);
        if (OUTF32) ((float*)Cv)[(size_t)m * Nd + n] = v;
        else        ((u16*)Cv)[(size_t)m * Nd + n] = f2bf(v);
      }
    }
  }
}

// ---------------- bf16 MFMA GEMM (64x64), async staging, token GEMMs ----------------
template<int RELU, int OUTF32>
__global__ __launch_bounds__(256) void gemm64(const u16* __restrict__ A,
                                              const u16* __restrict__ WT,
                                              const float* __restrict__ bias,
                                              void* __restrict__ Cv,
                                              int Kd, int Nd){
  __shared__ u16 As[64][32];
  __shared__ u16 Bs[64][32];
  const int t = threadIdx.x;
  const int bm = blockIdx.y << 6;
  const int bn = blockIdx.x << 6;
  const int wave = t >> 6;
  const int lane = t & 63;
  const int wm = (wave & 1) << 5;
  const int wn = (wave >> 1) << 5;
  const int lm = lane & 15;
  const int lk = (lane >> 4) << 3;
  u16* AsF = &As[0][0];
  u16* BsF = &Bs[0][0];
  const int wbase = wave << 6;
  f32x4 acc[2][2] = {};
  for (int k0 = 0; k0 < Kd; k0 += 32){
    {
      int r = t >> 2;
      int c = (t & 3) << 3;
      int dst = wbase << 3;
      ld_g2l(A  + (size_t)(bm + r) * Kd + k0 + c, AsF + dst);
      ld_g2l(WT + (size_t)(bn + r) * Kd + k0 + c, BsF + dst);
    }
    __syncthreads();
    short8 af[2], bfr[2];
#pragma unroll
    for (int mt = 0; mt < 2; mt++) af[mt] = *(const short8*)&As[wm + (mt << 4) + lm][lk];
#pragma unroll
    for (int nt = 0; nt < 2; nt++) bfr[nt] = *(const short8*)&Bs[wn + (nt << 4) + lm][lk];
#pragma unroll
    for (int mt = 0; mt < 2; mt++)
#pragma unroll
      for (int nt = 0; nt < 2; nt++)
        acc[mt][nt] = __builtin_amdgcn_mfma_f32_16x16x32_bf16(af[mt], bfr[nt], acc[mt][nt], 0, 0, 0);
    __syncthreads();
  }
#pragma unroll
  for (int nt = 0; nt < 2; nt++){
    int n = bn + wn + (nt << 4) + lm;
    float bia = bias[n];
#pragma unroll
    for (int mt = 0; mt < 2; mt++){
#pragma unroll
      for (int r2 = 0; r2 < 4; r2++){
        int m = bm + wm + (mt << 4) + ((lane >> 4) << 2) + r2;
        float v = acc[mt][nt][r2] + bia;
        if (RELU) v = fmaxf(v, 0.0f);
        if (OUTF32) ((float*)Cv)[(size_t)m * Nd + n] = v;
        else        ((u16*)Cv)[(size_t)m * Nd + n] = f2bf(v);
      }
    }
  }
}

// ---------------- GEMM + fused max-pool (128x128), async staging ----------------
__global__ __launch_bounds__(256) void gemm_pool(const u16* __restrict__ A,
                                                 const u16* __restrict__ WT,
                                                 const float* __restrict__ bias,
                                                 u16* __restrict__ pooled,
                                                 int Kd, int Nd, int groupBase){
  __shared__ u16 As[128][32];
  __shared__ u16 Bs[128][32];
  const int t = threadIdx.x;
  const int bm = blockIdx.y << 7;
  const int bn = blockIdx.x << 7;
  const int wave = t >> 6;
  const int lane = t & 63;
  const int wm = (wave & 1) << 6;
  const int wn = (wave >> 1) << 6;
  const int lm = lane & 15;
  const int lk = (lane >> 4) << 3;
  u16* AsF = &As[0][0];
  u16* BsF = &Bs[0][0];
  const int wbase = wave << 6;
  f32x4 acc[4][4] = {};
  for (int k0 = 0; k0 < Kd; k0 += 32){
#pragma unroll
    for (int it = 0; it < 2; it++){
      int slot = t + (it << 8);
      int r = slot >> 2;
      int c = (slot & 3) << 3;
      int dst = (wbase + (it << 8)) << 3;
      ld_g2l(A  + (size_t)(bm + r) * Kd + k0 + c, AsF + dst);
      ld_g2l(WT + (size_t)(bn + r) * Kd + k0 + c, BsF + dst);
    }
    __syncthreads();
    short8 af[4], bfr[4];
#pragma unroll
    for (int mt = 0; mt < 4; mt++) af[mt] = *(const short8*)&As[wm + (mt << 4) + lm][lk];
#pragma unroll
    for (int nt = 0; nt < 4; nt++) bfr[nt] = *(const short8*)&Bs[wn + (nt << 4) + lm][lk];
#pragma unroll
    for (int mt = 0; mt < 4; mt++)
#pragma unroll
      for (int nt = 0; nt < 4; nt++)
        acc[mt][nt] = __builtin_amdgcn_mfma_f32_16x16x32_bf16(af[mt], bfr[nt], acc[mt][nt], 0, 0, 0);
    __syncthreads();
  }
  // each (mt) tile's 16 rows are exactly one pooling group
#pragma unroll
  for (int nt = 0; nt < 4; nt++){
    int n = bn + wn + (nt << 4) + lm;
    float bia = bias[n];
#pragma unroll
    for (int mt = 0; mt < 4; mt++){
      f32x4 a = acc[mt][nt];
      float v = fmaxf(fmaxf(a[0], a[1]), fmaxf(a[2], a[3]));
      v = fmaxf(v, __shfl_xor(v, 16));
      v = fmaxf(v, __shfl_xor(v, 32));
      if ((lane >> 4) == 0){
        int g = groupBase + (bm >> 4) + (wm >> 4) + mt;
        pooled[(size_t)g * Nd + n] = f2bf(v + bia);
      }
    }
  }
}

// ---------------- tier fallback (f32) ----------------
__global__ __launch_bounds__(256) void fill_diag(float* __restrict__ out, size_t out_elems){
  size_t i = (size_t)blockIdx.x * 256 + threadIdx.x;
  if (i >= out_elems) return;
  size_t maskStart = (size_t)B_ * M_ * D_ + (size_t)B_ * M_ * 4;
  out[i] = (i >= maskStart) ? 1.0f : 0.0f;
}

extern "C" void kernel_launch(void* const* d_in, const int* in_sizes, int n_in,
                              void* d_out, int out_size, void* d_ws, size_t ws_size,
                              hipStream_t stream){
  (void)in_sizes; (void)n_in;
  const float* coords   = (const float*)d_in[0];
  const float* features = (const float*)d_in[1];
  const float* W0 = (const float*)d_in[2];  const float* b0 = (const float*)d_in[3];
  const float* W1 = (const float*)d_in[4];  const float* b1 = (const float*)d_in[5];
  const float* W2 = (const float*)d_in[6];  const float* b2 = (const float*)d_in[7];
  const float* W3 = (const float*)d_in[8];  const float* b3 = (const float*)d_in[9];
  const float* Wn0 = (const float*)d_in[10]; const float* bn0 = (const float*)d_in[11];
  const float* Wn1 = (const float*)d_in[12]; const float* bn1 = (const float*)d_in[13];
  float* out = (float*)d_out;
  const size_t out_elems = (size_t)out_size;

  char* ws = (char*)d_ws;
  const size_t o_pub  = 0;            // 32,768 (1024 centroids x 4 u64 publish slots)
  const size_t o_knn  = 32768;        // 65,536 -> 98,304 (knn, FPS order)
  const size_t o_invp = 98304;        // 4,096 (sorted pos -> fps index)
  const size_t o_Wb   = 131072;       // 4,587,520 bf16 W1t..Wn1t (transposed)
  const size_t o_pool = 4718592;      // 1,572,864 bf16 [1024,768]
  const size_t o_t1   = 6291456;      // 1,572,864
  const size_t o_chunk= 7864320;      // regA (R*1536 B) + regB (R*1024 B)
  const int ROWS = B_ * M_ * K_;      // 16384
  (void)o_pub;

  int R = 16384;
  while (R > 128 && o_chunk + (size_t)R * 2560 > ws_size) R >>= 1;
  if (d_ws == nullptr || o_chunk + (size_t)R * 2560 > ws_size){
    fill_diag<<<(int)((out_elems + 255) / 256), 256, 0, stream>>>(out, out_elems);
    return;
  }

  u64* cpub = (u64*)(ws + o_pub);
  int* knnb = (int*)(ws + o_knn);
  int* invp = (int*)(ws + o_invp);
  u16* Wb   = (u16*)(ws + o_Wb);
  u16* W1t  = Wb;               u16* W2t  = Wb + 131072;
  u16* W3t  = Wb + 524288;      u16* Wn0t = Wb + 1114112;
  u16* Wn1t = Wb + 1703936;
  u16* pooled = (u16*)(ws + o_pool);
  u16* t1     = (u16*)(ws + o_t1);
  u16* regA   = (u16*)(ws + o_chunk);                      // h1 [R,256] then h3 [R,768]
  u16* regB   = (u16*)(ws + o_chunk + (size_t)R * 1536);   // h2 [R,512]

  // clear publish tags (stale across graph replays), then the mega-fused launch.
  // The 84KB static LDS arena enforces 1 block/CU (r12's co-residency tax was +72us).
  zero_pub<<<16, 256, 0, stream>>>(cpub);
  fps_conv<<<816, 512, 0, stream>>>(coords, out, out_elems,
                                    W1, W2, W3, Wn0, Wn1, Wb,
                                    cpub, invp, knnb);

  for (int rowBase = 0; rowBase < ROWS; rowBase += R){
    gather_l0<<<R / 32, 256, 0, stream>>>(features, knnb, invp, W0, b0, regA, rowBase);
    gemm_bf16<1,0><<<dim3(4, R / 128), 256, 0, stream>>>(regA, W1t, b1, regB, 256, 512);
    gemm_bf16<1,0><<<dim3(6, R / 128), 256, 0, stream>>>(regB, W2t, b2, regA, 512, 768);
    gemm_pool<<<dim3(6, R / 128), 256, 0, stream>>>(regA, W3t, b3, pooled, 768, 768, rowBase >> 4);
  }

  gemm64<1,0><<<dim3(12, (B_ * M_) / 64), 256, 0, stream>>>(pooled, Wn0t, bn0, t1, 768, 768);
  gemm64<0,1><<<dim3(12, (B_ * M_) / 64), 256, 0, stream>>>(t1, Wn1t, bn1, out, 768, 768);
}

// Round 16
// 498.041 us; speedup vs baseline: 1.0066x; 1.0066x over previous
//
#include <hip/hip_runtime.h>

#define B_ 8
#define N_ 16384
#define F_ 6
#define M_ 128
#define K_ 16
#define D_ 768

typedef unsigned short u16;
typedef unsigned int u32;
typedef unsigned long long u64;
typedef __attribute__((ext_vector_type(8))) short short8;
typedef __attribute__((ext_vector_type(4))) float f32x4;
typedef __attribute__((ext_vector_type(2))) float f32x2;

__device__ __forceinline__ u16 f2bf(float f){
  union { float f; u32 i; } v; v.f = f;
  u32 x = v.i;
  u32 r = x + 0x7FFFu + ((x >> 16) & 1u);
  return (u16)(r >> 16);
}

// async 16B global->LDS (dest = wave-uniform base + lane*16)
__device__ __forceinline__ void ld_g2l(const u16* g, u16* l){
  __builtin_amdgcn_global_load_lds((const __attribute__((address_space(1))) u32*)g,
                                   (__attribute__((address_space(3))) u32*)l, 16, 0, 0);
}

// VOLATILE asm 16B load: result cannot be rematerialized from memory by LLVM.
__device__ __forceinline__ f32x4 ld_x4(const float* p){
  f32x4 r;
  asm volatile("global_load_dwordx4 %0, %1, off" : "=v"(r) : "v"(p) : "memory");
  return r;
}

// DPP self-max/min steps (chain row_shr:1,2,4,8 + row_bcast:15,31 -> result in lane 63;
// harness-verified rounds 6/7/10-14).
template<int CTRL>
__device__ __forceinline__ float dppmax(float v){
  union { float f; int i; } a, r;
  a.f = v;
  r.i = __builtin_amdgcn_update_dpp(a.i, a.i, CTRL, 0xF, 0xF, false);
  return fmaxf(v, r.f);
}
template<int CTRL>
__device__ __forceinline__ float dppmin(float v){
  union { float f; int i; } a, r;
  a.f = v;
  r.i = __builtin_amdgcn_update_dpp(a.i, a.i, CTRL, 0xF, 0xF, false);
  return fminf(v, r.f);
}
template<int CTRL>
__device__ __forceinline__ int dppimin(int v){
  int r = __builtin_amdgcn_update_dpp(v, v, CTRL, 0xF, 0xF, false);
  return (r < v) ? r : v;
}

// Publish one centroid: 4 self-validating u64 words ((m+1)<<32 | float_bits), relaxed
// agent-scope stores. Each word carries its own tag -> partial visibility is safe.
__device__ __forceinline__ void pub_cent(u64* pb, int m, float x, float y, float z, float w){
  union { float f; u32 u; } c0, c1, c2, c3;
  c0.f = x; c1.f = y; c2.f = z; c3.f = w;
  u64 tag = ((u64)(u32)(m + 1)) << 32;
  __hip_atomic_store(pb + 0, tag | c0.u, __ATOMIC_RELAXED, __HIP_MEMORY_SCOPE_AGENT);
  __hip_atomic_store(pb + 1, tag | c1.u, __ATOMIC_RELAXED, __HIP_MEMORY_SCOPE_AGENT);
  __hip_atomic_store(pb + 2, tag | c2.u, __ATOMIC_RELAXED, __HIP_MEMORY_SCOPE_AGENT);
  __hip_atomic_store(pb + 3, tag | c3.u, __ATOMIC_RELAXED, __HIP_MEMORY_SCOPE_AGENT);
}

// ---------------- zero the centroid publish slots (stale tags across graph replays) ----------------
__global__ __launch_bounds__(256) void zero_pub(u64* __restrict__ pub){
  pub[(size_t)blockIdx.x * 256 + threadIdx.x] = 0ull;
}

// ---------------- MEGA-FUSED: FPS (0..7) + weight conv (8..567) + knn workers (568..815) ----------------
// r14 verdict: LDS fence took (86016) but duration unchanged -> co-residency falsified.
// Remaining r11->r12 deltas: publish/poll LLC contention. r15 decongests it:
// (1) knn poll granularity s_sleep(2)->s_sleep(32): 16x less read pressure on the
//     publish lines (first job round has ~184 idle spinners for ~60us);
// (2) rotate the publishing wave (step&7): each wave gets ~8 steps for its 4 LLC
//     stores to retire before ITS barrier vmcnt(0) drain (vs wave0 paying every step).
// All threads hold the winner coords post-combine (uniform scan + broadcast loads),
// so any wave can publish. 84KB LDS arena keeps 1 block/CU (verified r14).
#define FPT 32   // fps: points per thread (512 thr)
#define KNW 248  // knn worker blocks
#define KNT 512
#define KPT 32
__global__ __launch_bounds__(512)
void fps_conv(const float* __restrict__ coords,
              float* __restrict__ out, size_t out_elems,
              const float* __restrict__ W1, const float* __restrict__ W2,
              const float* __restrict__ W3, const float* __restrict__ Wn0,
              const float* __restrict__ Wn1, u16* __restrict__ Wb,
              u64* __restrict__ cpub, int* __restrict__ invp,
              int* __restrict__ knn_fps){
#pragma clang fp contract(off)
  // 84KB occupancy fence: 2 blocks would need 168KB > 160KB -> 1 block/CU guaranteed.
  __shared__ __attribute__((aligned(16))) char smem[86016];
  u16 (*tile)[65] = (u16(*)[65])smem;                  // conv: 64x65 u16 = 8320 B (conv-only)
  f32x4* carr     = (f32x4*)smem;                      // fps: 2048 B (fps-only; disjoint branch)
  float (*swv)[8] = (float(*)[8])(smem + 8320);        // fps+knn: 64 B
  int   (*swi)[8] = (int(*)[8])(smem + 8384);          // fps+knn: 64 B
  int*   s_bi     = (int*)(smem + 8448);
  f32x4* scent    = (f32x4*)(smem + 8464);
  int blk = blockIdx.x;
  int t = threadIdx.x;

  if (blk >= 8 && blk < 568){
    // ---------------- weight conversion branch (512 threads) ----------------
    int cblk = blk - 8;
    const float* W; u16* WT; int K, N, lb;
    if      (cblk < 32)  { W = W1;  WT = Wb;           K = 256; N = 512; lb = cblk; }
    else if (cblk < 128) { W = W2;  WT = Wb + 131072;  K = 512; N = 768; lb = cblk - 32; }
    else if (cblk < 272) { W = W3;  WT = Wb + 524288;  K = 768; N = 768; lb = cblk - 128; }
    else if (cblk < 416) { W = Wn0; WT = Wb + 1114112; K = 768; N = 768; lb = cblk - 272; }
    else                 { W = Wn1; WT = Wb + 1703936; K = 768; N = 768; lb = cblk - 416; }
    int tiles_n = N >> 6;
    int tk = lb / tiles_n, tn = lb % tiles_n;
    int k0 = tk << 6, n0 = tn << 6;
#pragma unroll
    for (int q = 0; q < 8; q++){
      int idx = q * 512 + t;
      int kk = idx >> 6, nn = idx & 63;
      tile[kk][nn] = f2bf(W[(size_t)(k0 + kk) * N + n0 + nn]);
    }
    __syncthreads();
#pragma unroll
    for (int q = 0; q < 8; q++){
      int idx = q * 512 + t;
      int nn = idx >> 6, kk = idx & 63;
      WT[(size_t)(n0 + nn) * K + k0 + kk] = tile[kk][nn];
    }
    return;
  }

  if (blk >= 568){
    // ---------------- knn worker branch: poll centroids, compute kNN (FPS order) ----------------
    int w = blk - 568;
    for (int p = w; p < B_ * M_; p += KNW){
      int m = p >> 3, b = p & 7;
      if (t == 0){
        const u64* pb = cpub + (((size_t)b << 7) + m) * 4;
        u32 want = (u32)(m + 1);
        u64 v0, v1, v2, v3;
        for (;;){
          v0 = __hip_atomic_load(pb + 0, __ATOMIC_RELAXED, __HIP_MEMORY_SCOPE_AGENT);
          v1 = __hip_atomic_load(pb + 1, __ATOMIC_RELAXED, __HIP_MEMORY_SCOPE_AGENT);
          v2 = __hip_atomic_load(pb + 2, __ATOMIC_RELAXED, __HIP_MEMORY_SCOPE_AGENT);
          v3 = __hip_atomic_load(pb + 3, __ATOMIC_RELAXED, __HIP_MEMORY_SCOPE_AGENT);
          if ((u32)(v0 >> 32) == want && (u32)(v1 >> 32) == want &&
              (u32)(v2 >> 32) == want && (u32)(v3 >> 32) == want) break;
          __builtin_amdgcn_s_sleep(32);            // ~2048cy: 16x less LLC poll pressure
        }
        union { u32 u; float f; } d0, d1, d2, d3;
        d0.u = (u32)v0; d1.u = (u32)v1; d2.u = (u32)v2; d3.u = (u32)v3;
        *scent = (f32x4){d0.f, d1.f, d2.f, d3.f};
      }
      __syncthreads();
      float cx = (*scent)[0], cy = (*scent)[1], cz = (*scent)[2], ct = (*scent)[3];
      const float* cb = coords + (size_t)b * N_ * 5;
      float dist[KPT];
#pragma unroll
      for (int j = 0; j < KPT; j++){
        size_t i = t + j * KNT;
        float dx=cb[i*5+1]-cx, dy=cb[i*5+2]-cy, dz=cb[i*5+3]-cz, dw=cb[i*5+4]-ct;
        float d = ((dx*dx + dy*dy) + dz*dz) + dw*dw;
        dist[j] = sqrtf(d);                          // IEEE f32 sqrt = np.sqrt(f32)
      }
      for (int r = 0; r < K_; r++){
        float bv = 3e38f; int bi = 1 << 30;
#pragma unroll
        for (int j = 0; j < KPT; j++){
          int i = t + j * KNT;
          float v = dist[j];
          if (v < bv){ bv = v; bi = i; }             // first-min kept (ascending own indices)
        }
        // value min via DPP; ties -> integer index-min DPP (lane order != index order)
        float rv = bv;
        rv = dppmin<0x111>(rv); rv = dppmin<0x112>(rv); rv = dppmin<0x114>(rv);
        rv = dppmin<0x118>(rv); rv = dppmin<0x142>(rv); rv = dppmin<0x143>(rv);
        union { float f; int i; } rmu; rmu.f = rv;
        union { int i; float f; } wmn; wmn.i = __builtin_amdgcn_readlane(rmu.i, 63);
        float wmin = wmn.f;
        int cand = (bv == wmin) ? bi : 0x7FFFFFFF;
        cand = dppimin<0x111>(cand); cand = dppimin<0x112>(cand); cand = dppimin<0x114>(cand);
        cand = dppimin<0x118>(cand); cand = dppimin<0x142>(cand); cand = dppimin<0x143>(cand);
        int wbi = __builtin_amdgcn_readlane(cand, 63);
        if ((t & 63) == 0){ swv[0][t >> 6] = wmin; swi[0][t >> 6] = wbi; }
        __syncthreads();
        if (t == 0){
          float fv = swv[0][0]; int fi = swi[0][0];
          for (int ww = 1; ww < 8; ww++){
            float wv = swv[0][ww]; int wi = swi[0][ww];
            if (wv < fv || (wv == fv && wi < fi)){ fv = wv; fi = wi; }
          }
          *s_bi = fi;
          knn_fps[(((size_t)b << 7) + m) * K_ + r] = fi & (N_ - 1);
        }
        __syncthreads();
        int wi = *s_bi;
#pragma unroll
        for (int j = 0; j < KPT; j++){
          if (t + j * KNT == wi) dist[j] = 3e38f;
        }
      }
    }
    return;
  }

  // ---------------- FPS branch (round-7 verbatim core + rotating publish) ----------------
  int b = blk;
  int lane = t & 63, wave = t >> 6;
  const float* cb = coords + (size_t)b * N_ * 5;
  const int base = t << 5;                       // first point index owned by this thread
  f32x4 p[FPT];
#pragma unroll
  for (int k = 0; k < FPT; k++){
    p[k] = ld_x4(cb + (size_t)(base + k) * 5 + 1);   // (x,y,z,w) of point base+k
  }
  float md[FPT];
#pragma unroll
  for (int k = 0; k < FPT; k++) md[k] = 1e30f;
  asm volatile("s_waitcnt vmcnt(0)" ::: "memory");   // drain the asm loads
  __builtin_amdgcn_sched_barrier(0);                 // rule #18: pin uses after the wait
  float cx = cb[1], cy = cb[2], cz = cb[3], ct = cb[4];
  if (t == 0){
    carr[0] = (f32x4){cx, cy, cz, ct};
    pub_cent(cpub + ((size_t)b << 7) * 4, 0, cx, cy, cz, ct);
  }
  for (int step = 1; step < M_; step++){
    float bv = -1.0f; int bl = 0;
#pragma unroll
    for (int k = 0; k < FPT; k++){
      float dx = p[k][0] - cx;
      float dy = p[k][1] - cy;
      float dz = p[k][2] - cz;
      float dw = p[k][3] - ct;
      float s = ((dx*dx + dy*dy) + dz*dz) + dw*dw;   // reference rounding order
      float m = fminf(s, md[k]);
      md[k] = m;
      if (m > bv){ bv = m; bl = k; }                 // ascending-index first-max
    }
    int bi = base + bl;                              // global point index
    float r = bv;
    r = dppmax<0x111>(r); r = dppmax<0x112>(r); r = dppmax<0x114>(r);
    r = dppmax<0x118>(r); r = dppmax<0x142>(r); r = dppmax<0x143>(r);
    union { float f; int i; } rm; rm.f = r;
    union { int i; float f; } wmu; wmu.i = __builtin_amdgcn_readlane(rm.i, 63);
    float wmax = wmu.f;                              // uniform (SGPR)
    u64 wmask = __ballot(bv == wmax);
    int srcL = (int)__ffsll((unsigned long long)wmask) - 1;  // lowest lane = lowest index
    int wbi = __builtin_amdgcn_readlane(bi, srcL);   // uniform winner index of this wave
    int par = step & 1;
    if (lane == 0){ swv[par][wave] = wmax; swi[par][wave] = wbi; }
    __syncthreads();                                 // only barrier per step
    float fv = swv[par][0]; int fi = swi[par][0];
#pragma unroll
    for (int w = 1; w < 8; w++){
      float v = swv[par][w];
      int  iw = swi[par][w];
      if (v > fv){ fv = v; fi = iw; }                // strict > keeps lowest wave (= lowest index)
    }
    int widx = __builtin_amdgcn_readfirstlane(fi);
    size_t wb = (size_t)widx * 5;
    cx = cb[wb+1]; cy = cb[wb+2]; cz = cb[wb+3]; ct = cb[wb+4];
    if (t == 0) carr[step] = (f32x4){cx, cy, cz, ct};
    // rotating publisher: wave (step&7), lane 0 — its stores get ~8 steps to retire
    // before this wave next stalls on a barrier vmcnt(0) drain.
    if (t == ((step & 7) << 6)){
      pub_cent(cpub + (((size_t)b << 7) + step) * 4, step, cx, cy, cz, ct);
    }
  }
  // ---- fused rank tail: stable argsort by centroid time -> out + invp ----
  __syncthreads();
  if (t < M_){
    f32x4 row = carr[t];
    float w = row[3];
    int rank = 0;
    for (int j = 0; j < M_; j++){
      float tj = carr[j][3];
      if (tj < w || (tj == w && j < t)) rank++;      // stable argsort semantics
    }
    invp[(b << 7) + rank] = t;                       // sorted pos -> fps index
    size_t co = (size_t)B_ * M_ * D_ + ((size_t)b * M_ + rank) * 4;
    if (co + 3 < out_elems){
      out[co+0]=row[0]; out[co+1]=row[1]; out[co+2]=row[2]; out[co+3]=w;
    }
    size_t mo = (size_t)B_ * M_ * D_ + (size_t)B_ * M_ * 4 + (size_t)b * M_ + t;
    if (mo < out_elems) out[mo] = 1.0f;              // mask = True -> 1.0f
  }
}

// ---------------- gather + layer0: 32 rows/block; knn in FPS order, remap via invp ----------------
__global__ __launch_bounds__(256) void gather_l0(const float* __restrict__ feat,
                                                 const int* __restrict__ knn,
                                                 const int* __restrict__ invp,
                                                 const float* __restrict__ W0,
                                                 const float* __restrict__ b0,
                                                 u16* __restrict__ h1,
                                                 int rowBase){
  __shared__ float sW[F_][256];
  __shared__ float sb[256];
  __shared__ float sfa[32][F_];
  int t = threadIdx.x;
#pragma unroll
  for (int k = 0; k < F_; k++) sW[k][t] = W0[k * 256 + t];
  sb[t] = b0[t];
  if (t < 32 * F_){
    int r = t / F_, k = t % F_;
    int grow = rowBase + blockIdx.x * 32 + r;
    int bb = grow >> 11;                          // /(M*K)=2048
    int ms = (grow >> 4) & 127;                   // sorted centroid position
    int kk = grow & 15;
    int mf = invp[(bb << 7) + ms];                // fps-order centroid index
    int idx = knn[((((size_t)bb << 7) + mf) << 4) + kk] & (N_ - 1);
    sfa[r][k] = feat[((size_t)bb * N_ + idx) * F_ + k];
  }
  __syncthreads();
#pragma unroll 4
  for (int r = 0; r < 32; r++){
    float acc = sb[t];
#pragma unroll
    for (int k = 0; k < F_; k++) acc = fmaf(sfa[r][k], sW[k][t], acc);
    int lrow = blockIdx.x * 32 + r;
    h1[(size_t)lrow * 256 + t] = f2bf(fmaxf(acc, 0.0f));
  }
}

// ---------------- bf16 MFMA GEMM (128x128), async global->LDS staging ----------------
template<int RELU, int OUTF32>
__global__ __launch_bounds__(256) void gemm_bf16(const u16* __restrict__ A,
                                                 const u16* __restrict__ WT,
                                                 const float* __restrict__ bias,
                                                 void* __restrict__ Cv,
                                                 int Kd, int Nd){
  __shared__ u16 As[128][32];
  __shared__ u16 Bs[128][32];
  const int t = threadIdx.x;
  const int bm = blockIdx.y << 7;
  const int bn = blockIdx.x << 7;
  const int wave = t >> 6;
  const int lane = t & 63;
  const int wm = (wave & 1) << 6;
  const int wn = (wave >> 1) << 6;
  const int lm = lane & 15;
  const int lk = (lane >> 4) << 3;
  u16* AsF = &As[0][0];
  u16* BsF = &Bs[0][0];
  const int wbase = wave << 6;               // t - lane
  f32x4 acc[4][4] = {};
  for (int k0 = 0; k0 < Kd; k0 += 32){
#pragma unroll
    for (int it = 0; it < 2; it++){
      int slot = t + (it << 8);
      int r = slot >> 2;
      int c = (slot & 3) << 3;
      int dst = (wbase + (it << 8)) << 3;    // u16 elements; +lane*16B by HW
      ld_g2l(A  + (size_t)(bm + r) * Kd + k0 + c, AsF + dst);
      ld_g2l(WT + (size_t)(bn + r) * Kd + k0 + c, BsF + dst);
    }
    __syncthreads();
    short8 af[4], bfr[4];
#pragma unroll
    for (int mt = 0; mt < 4; mt++) af[mt] = *(const short8*)&As[wm + (mt << 4) + lm][lk];
#pragma unroll
    for (int nt = 0; nt < 4; nt++) bfr[nt] = *(const short8*)&Bs[wn + (nt << 4) + lm][lk];
#pragma unroll
    for (int mt = 0; mt < 4; mt++)
#pragma unroll
      for (int nt = 0; nt < 4; nt++)
        acc[mt][nt] = __builtin_amdgcn_mfma_f32_16x16x32_bf16(af[mt], bfr[nt], acc[mt][nt], 0, 0, 0);
    __syncthreads();
  }
#pragma unroll
  for (int nt = 0; nt < 4; nt++){
    int n = bn + wn + (nt << 4) + lm;
    float bia = bias[n];
#pragma unroll
    for (int mt = 0; mt < 4; mt++){
#pragma unroll
      for (int r2 = 0; r2 < 4; r2++){
        int m = bm + wm + (mt << 4) + ((lane >> 4) << 2) + r2;
        float v = acc[mt][nt][r2] + bia;
        if (RELU) v = fmaxf(v, 0.0f);
        if (OUTF32) ((float*)Cv)[(size_t)m * Nd + n] = v;
        else        ((u16*)Cv)[(size_t)m * Nd + n] = f2bf(v);
      }
    }
  }
}

// ---------------- bf16 MFMA GEMM (64x64), async staging, token GEMMs ----------------
template<int RELU, int OUTF32>
__global__ __launch_bounds__(256) void gemm64(const u16* __restrict__ A,
                                              const u16* __restrict__ WT,
                                              const float* __restrict__ bias,
                                              void* __restrict__ Cv,
                                              int Kd, int Nd){
  __shared__ u16 As[64][32];
  __shared__ u16 Bs[64][32];
  const int t = threadIdx.x;
  const int bm = blockIdx.y << 6;
  const int bn = blockIdx.x << 6;
  const int wave = t >> 6;
  const int lane = t & 63;
  const int wm = (wave & 1) << 5;
  const int wn = (wave >> 1) << 5;
  const int lm = lane & 15;
  const int lk = (lane >> 4) << 3;
  u16* AsF = &As[0][0];
  u16* BsF = &Bs[0][0];
  const int wbase = wave << 6;
  f32x4 acc[2][2] = {};
  for (int k0 = 0; k0 < Kd; k0 += 32){
    {
      int r = t >> 2;
      int c = (t & 3) << 3;
      int dst = wbase << 3;
      ld_g2l(A  + (size_t)(bm + r) * Kd + k0 + c, AsF + dst);
      ld_g2l(WT + (size_t)(bn + r) * Kd + k0 + c, BsF + dst);
    }
    __syncthreads();
    short8 af[2], bfr[2];
#pragma unroll
    for (int mt = 0; mt < 2; mt++) af[mt] = *(const short8*)&As[wm + (mt << 4) + lm][lk];
#pragma unroll
    for (int nt = 0; nt < 2; nt++) bfr[nt] = *(const short8*)&Bs[wn + (nt << 4) + lm][lk];
#pragma unroll
    for (int mt = 0; mt < 2; mt++)
#pragma unroll
      for (int nt = 0; nt < 2; nt++)
        acc[mt][nt] = __builtin_amdgcn_mfma_f32_16x16x32_bf16(af[mt], bfr[nt], acc[mt][nt], 0, 0, 0);
    __syncthreads();
  }
#pragma unroll
  for (int nt = 0; nt < 2; nt++){
    int n = bn + wn + (nt << 4) + lm;
    float bia = bias[n];
#pragma unroll
    for (int mt = 0; mt < 2; mt++){
#pragma unroll
      for (int r2 = 0; r2 < 4; r2++){
        int m = bm + wm + (mt << 4) + ((lane >> 4) << 2) + r2;
        float v = acc[mt][nt][r2] + bia;
        if (RELU) v = fmaxf(v, 0.0f);
        if (OUTF32) ((float*)Cv)[(size_t)m * Nd + n] = v;
        else        ((u16*)Cv)[(size_t)m * Nd + n] = f2bf(v);
      }
    }
  }
}

// ---------------- GEMM + fused max-pool (128x128), async staging ----------------
__global__ __launch_bounds__(256) void gemm_pool(const u16* __restrict__ A,
                                                 const u16* __restrict__ WT,
                                                 const float* __restrict__ bias,
                                                 u16* __restrict__ pooled,
                                                 int Kd, int Nd, int groupBase){
  __shared__ u16 As[128][32];
  __shared__ u16 Bs[128][32];
  const int t = threadIdx.x;
  const int bm = blockIdx.y << 7;
  const int bn = blockIdx.x << 7;
  const int wave = t >> 6;
  const int lane = t & 63;
  const int wm = (wave & 1) << 6;
  const int wn = (wave >> 1) << 6;
  const int lm = lane & 15;
  const int lk = (lane >> 4) << 3;
  u16* AsF = &As[0][0];
  u16* BsF = &Bs[0][0];
  const int wbase = wave << 6;
  f32x4 acc[4][4] = {};
  for (int k0 = 0; k0 < Kd; k0 += 32){
#pragma unroll
    for (int it = 0; it < 2; it++){
      int slot = t + (it << 8);
      int r = slot >> 2;
      int c = (slot & 3) << 3;
      int dst = (wbase + (it << 8)) << 3;
      ld_g2l(A  + (size_t)(bm + r) * Kd + k0 + c, AsF + dst);
      ld_g2l(WT + (size_t)(bn + r) * Kd + k0 + c, BsF + dst);
    }
    __syncthreads();
    short8 af[4], bfr[4];
#pragma unroll
    for (int mt = 0; mt < 4; mt++) af[mt] = *(const short8*)&As[wm + (mt << 4) + lm][lk];
#pragma unroll
    for (int nt = 0; nt < 4; nt++) bfr[nt] = *(const short8*)&Bs[wn + (nt << 4) + lm][lk];
#pragma unroll
    for (int mt = 0; mt < 4; mt++)
#pragma unroll
      for (int nt = 0; nt < 4; nt++)
        acc[mt][nt] = __builtin_amdgcn_mfma_f32_16x16x32_bf16(af[mt], bfr[nt], acc[mt][nt], 0, 0, 0);
    __syncthreads();
  }
  // each (mt) tile's 16 rows are exactly one pooling group
#pragma unroll
  for (int nt = 0; nt < 4; nt++){
    int n = bn + wn + (nt << 4) + lm;
    float bia = bias[n];
#pragma unroll
    for (int mt = 0; mt < 4; mt++){
      f32x4 a = acc[mt][nt];
      float v = fmaxf(fmaxf(a[0], a[1]), fmaxf(a[2], a[3]));
      v = fmaxf(v, __shfl_xor(v, 16));
      v = fmaxf(v, __shfl_xor(v, 32));
      if ((lane >> 4) == 0){
        int g = groupBase + (bm >> 4) + (wm >> 4) + mt;
        pooled[(size_t)g * Nd + n] = f2bf(v + bia);
      }
    }
  }
}

// ---------------- tier fallback (f32) ----------------
__global__ __launch_bounds__(256) void fill_diag(float* __restrict__ out, size_t out_elems){
  size_t i = (size_t)blockIdx.x * 256 + threadIdx.x;
  if (i >= out_elems) return;
  size_t maskStart = (size_t)B_ * M_ * D_ + (size_t)B_ * M_ * 4;
  out[i] = (i >= maskStart) ? 1.0f : 0.0f;
}

extern "C" void kernel_launch(void* const* d_in, const int* in_sizes, int n_in,
                              void* d_out, int out_size, void* d_ws, size_t ws_size,
                              hipStream_t stream){
  (void)in_sizes; (void)n_in;
  const float* coords   = (const float*)d_in[0];
  const float* features = (const float*)d_in[1];
  const float* W0 = (const float*)d_in[2];  const float* b0 = (const float*)d_in[3];
  const float* W1 = (const float*)d_in[4];  const float* b1 = (const float*)d_in[5];
  const float* W2 = (const float*)d_in[6];  const float* b2 = (const float*)d_in[7];
  const float* W3 = (const float*)d_in[8];  const float* b3 = (const float*)d_in[9];
  const float* Wn0 = (const float*)d_in[10]; const float* bn0 = (const float*)d_in[11];
  const float* Wn1 = (const float*)d_in[12]; const float* bn1 = (const float*)d_in[13];
  float* out = (float*)d_out;
  const size_t out_elems = (size_t)out_size;

  char* ws = (char*)d_ws;
  const size_t o_pub  = 0;            // 32,768 (1024 centroids x 4 u64 publish slots)
  const size_t o_knn  = 32768;        // 65,536 -> 98,304 (knn, FPS order)
  const size_t o_invp = 98304;        // 4,096 (sorted pos -> fps index)
  const size_t o_Wb   = 131072;       // 4,587,520 bf16 W1t..Wn1t (transposed)
  const size_t o_pool = 4718592;      // 1,572,864 bf16 [1024,768]
  const size_t o_t1   = 6291456;      // 1,572,864
  const size_t o_chunk= 7864320;      // regA (R*1536 B) + regB (R*1024 B)
  const int ROWS = B_ * M_ * K_;      // 16384
  (void)o_pub;

  int R = 16384;
  while (R > 128 && o_chunk + (size_t)R * 2560 > ws_size) R >>= 1;
  if (d_ws == nullptr || o_chunk + (size_t)R * 2560 > ws_size){
    fill_diag<<<(int)((out_elems + 255) / 256), 256, 0, stream>>>(out, out_elems);
    return;
  }

  u64* cpub = (u64*)(ws + o_pub);
  int* knnb = (int*)(ws + o_knn);
  int* invp = (int*)(ws + o_invp);
  u16* Wb   = (u16*)(ws + o_Wb);
  u16* W1t  = Wb;               u16* W2t  = Wb + 131072;
  u16* W3t  = Wb + 524288;      u16* Wn0t = Wb + 1114112;
  u16* Wn1t = Wb + 1703936;
  u16* pooled = (u16*)(ws + o_pool);
  u16* t1     = (u16*)(ws + o_t1);
  u16* regA   = (u16*)(ws + o_chunk);                      // h1 [R,256] then h3 [R,768]
  u16* regB   = (u16*)(ws + o_chunk + (size_t)R * 1536);   // h2 [R,512]

  // clear publish tags (stale across graph replays), then the mega-fused launch.
  zero_pub<<<16, 256, 0, stream>>>(cpub);
  fps_conv<<<816, 512, 0, stream>>>(coords, out, out_elems,
                                    W1, W2, W3, Wn0, Wn1, Wb,
                                    cpub, invp, knnb);

  for (int rowBase = 0; rowBase < ROWS; rowBase += R){
    gather_l0<<<R / 32, 256, 0, stream>>>(features, knnb, invp, W0, b0, regA, rowBase);
    gemm_bf16<1,0><<<dim3(4, R / 128), 256, 0, stream>>>(regA, W1t, b1, regB, 256, 512);
    gemm_bf16<1,0><<<dim3(6, R / 128), 256, 0, stream>>>(regB, W2t, b2, regA, 512, 768);
    gemm_pool<<<dim3(6, R / 128), 256, 0, stream>>>(regA, W3t, b3, pooled, 768, 768, rowBase >> 4);
  }

  gemm64<1,0><<<dim3(12, (B_ * M_) / 64), 256, 0, stream>>>(pooled, Wn0t, bn0, t1, 768, 768);
  gemm64<0,1><<<dim3(12, (B_ * M_) / 64), 256, 0, stream>>>(t1, Wn1t, bn1, out, 768, 768);
}